// Round 1
// baseline (343.304 us; speedup 1.0000x reference)
//
#include <hip/hip_runtime.h>
#include <stdint.h>

#define BATCH 4096
#define NTX   4096   // NT*NX flattened sites
#define NH    2048   // N_HALF
#define KDIM  2048

#define BM 128
#define BN 128
#define BK 32

typedef __bf16 bf16x8 __attribute__((ext_vector_type(8)));
typedef float  f32x4  __attribute__((ext_vector_type(4)));

// RNE float -> bf16 (bit-twiddle; avoids any bf16 intrinsic portability risk)
__device__ __forceinline__ unsigned short f2bf(float f) {
    union { float f; unsigned u; } v; v.f = f;
    unsigned u = v.u;
    unsigned r = u + 0x7fffu + ((u >> 16) & 1u);
    return (unsigned short)(r >> 16);
}

__device__ __forceinline__ float fast_tanh(float x) {
    // tanh(x) = 1 - 2/(exp(2x)+1); exp overflow/underflow saturates correctly
    float e = __expf(x + x);
    return 1.f - 2.f / (e + 1.f);
}

typedef __attribute__((address_space(1))) void gvoid;
typedef __attribute__((address_space(3))) void lvoid;

__device__ __forceinline__ void async16(const unsigned short* g, unsigned short* l) {
    __builtin_amdgcn_global_load_lds((gvoid*)(void*)g, (lvoid*)l, 16, 0, 0);
}

// ---------------------------------------------------------------------------
// prep: split phi -> B-half bf16; convert W_s, W_t -> bf16; zero logdet accum
// ---------------------------------------------------------------------------
__global__ void prep(const float* __restrict__ phi,
                     const float* __restrict__ Wsf,
                     const float* __restrict__ Wtf,
                     unsigned short* __restrict__ Bbf,
                     unsigned short* __restrict__ Wsb,
                     unsigned short* __restrict__ Wtb,
                     float* __restrict__ ld)
{
    const int tid    = blockIdx.x * blockDim.x + threadIdx.x;
    const int stride = gridDim.x * blockDim.x;

    // B-half: phi[b][2i] -> Bbf[b][i]; process 8 floats (4 sites) per iter
    const float4* p4 = (const float4*)phi;
    for (int i = tid; i < (BATCH * NH / 4); i += stride) {
        float4 u = p4[2 * i], v = p4[2 * i + 1];
        uint2 o;
        o.x = (unsigned)f2bf(u.x) | ((unsigned)f2bf(u.z) << 16);
        o.y = (unsigned)f2bf(v.x) | ((unsigned)f2bf(v.z) << 16);
        ((uint2*)Bbf)[i] = o;
    }

    // W_s, W_t: 8 floats per iter -> 16B bf16 store
    const float4* ws4 = (const float4*)Wsf;
    const float4* wt4 = (const float4*)Wtf;
    for (int i = tid; i < (NH * KDIM / 8); i += stride) {
        float4 u = ws4[2 * i], v = ws4[2 * i + 1];
        uint4 o;
        o.x = (unsigned)f2bf(u.x) | ((unsigned)f2bf(u.y) << 16);
        o.y = (unsigned)f2bf(u.z) | ((unsigned)f2bf(u.w) << 16);
        o.z = (unsigned)f2bf(v.x) | ((unsigned)f2bf(v.y) << 16);
        o.w = (unsigned)f2bf(v.z) | ((unsigned)f2bf(v.w) << 16);
        ((uint4*)Wsb)[i] = o;
        u = wt4[2 * i]; v = wt4[2 * i + 1];
        o.x = (unsigned)f2bf(u.x) | ((unsigned)f2bf(u.y) << 16);
        o.y = (unsigned)f2bf(u.z) | ((unsigned)f2bf(u.w) << 16);
        o.z = (unsigned)f2bf(v.x) | ((unsigned)f2bf(v.y) << 16);
        o.w = (unsigned)f2bf(v.z) | ((unsigned)f2bf(v.w) << 16);
        ((uint4*)Wtb)[i] = o;
    }

    for (int i = tid; i < BATCH; i += stride) ld[i] = 0.f;
}

// ---------------------------------------------------------------------------
// Dual GEMM + coupling epilogue.
//   s_raw = X @ Ws^T + bs ; t = X @ Wt^T + bt
//   s = tanh(s_raw); val = phi[b][2n+parity]*exp(s) + t
//   out[b][2n+parity] = val ; (pass1) Xout[b][n] = bf16(val) ; ld[b] += sum(s)
// X:[4096][2048] bf16, W*:[2048][2048] bf16 row-major (K contiguous).
// 128x128 tile, BK=32, 256 thr = 2x2 waves, each wave 64x64 per matrix.
// ---------------------------------------------------------------------------
__global__ __launch_bounds__(256, 2) void coupling_gemm(
    const unsigned short* __restrict__ X,
    const unsigned short* __restrict__ Wsb,
    const unsigned short* __restrict__ Wtb,
    const float* __restrict__ bs,
    const float* __restrict__ bt,
    const float* __restrict__ phi,
    float* __restrict__ out,
    unsigned short* __restrict__ Xout,
    float* __restrict__ ld,
    int parity)
{
    __shared__ unsigned short Xs[BM * BK];
    __shared__ unsigned short Ss[BN * BK];
    __shared__ unsigned short Ts[BN * BK];

    const int tid = threadIdx.x;
    const int m0 = blockIdx.x * BM;
    const int n0 = blockIdx.y * BN;

    f32x4 acc_s[4][4], acc_t[4][4];
    const f32x4 zf = {0.f, 0.f, 0.f, 0.f};
#pragma unroll
    for (int i = 0; i < 4; i++)
#pragma unroll
        for (int j = 0; j < 4; j++) { acc_s[i][j] = zf; acc_t[i][j] = zf; }

    // staging: tile row-major [128][32] bf16 (64B rows); thread covers 16B
    // chunk0 at byte tid*16 (row tid/4, col (tid%4)*8), chunk1 at +4096B (+64 rows)
    const int rowA = tid >> 2;
    const int colE = (tid & 3) * 8;
    const unsigned short* Xg = X   + (size_t)(m0 + rowA) * KDIM + colE;
    const unsigned short* Sg = Wsb + (size_t)(n0 + rowA) * KDIM + colE;
    const unsigned short* Tg = Wtb + (size_t)(n0 + rowA) * KDIM + colE;
    const size_t rstride = (size_t)64 * KDIM;
    unsigned short* Xl = Xs + tid * 8;
    unsigned short* Sl = Ss + tid * 8;
    unsigned short* Tl = Ts + tid * 8;

    const int wave = tid >> 6;
    const int lane = tid & 63;
    const int wm = (wave >> 1) * 64;
    const int wn = (wave & 1) * 64;
    const int lrow = lane & 15;
    const int lko  = (lane >> 4) * 8;

    for (int k0 = 0; k0 < KDIM; k0 += BK) {
        __syncthreads();
        async16(Xg + k0,           Xl);
        async16(Xg + k0 + rstride, Xl + 2048);
        async16(Sg + k0,           Sl);
        async16(Sg + k0 + rstride, Sl + 2048);
        async16(Tg + k0,           Tl);
        async16(Tg + k0 + rstride, Tl + 2048);
        __syncthreads();

        bf16x8 a[4], vs[4], vt[4];
#pragma unroll
        for (int i = 0; i < 4; i++) {
            a[i]  = *(const bf16x8*)(Xs + (wm + i * 16 + lrow) * BK + lko);
            vs[i] = *(const bf16x8*)(Ss + (wn + i * 16 + lrow) * BK + lko);
            vt[i] = *(const bf16x8*)(Ts + (wn + i * 16 + lrow) * BK + lko);
        }
#pragma unroll
        for (int mi = 0; mi < 4; mi++)
#pragma unroll
            for (int ni = 0; ni < 4; ni++) {
                acc_s[mi][ni] = __builtin_amdgcn_mfma_f32_16x16x32_bf16(
                    a[mi], vs[ni], acc_s[mi][ni], 0, 0, 0);
                acc_t[mi][ni] = __builtin_amdgcn_mfma_f32_16x16x32_bf16(
                    a[mi], vt[ni], acc_t[mi][ni], 0, 0, 0);
            }
    }

    // epilogue: C/D layout col=lane&15, row=(lane>>4)*4+reg
#pragma unroll
    for (int mi = 0; mi < 4; mi++) {
#pragma unroll
        for (int r = 0; r < 4; r++) {
            const int brow = m0 + wm + mi * 16 + (lane >> 4) * 4 + r;
            float ssum = 0.f;
#pragma unroll
            for (int ni = 0; ni < 4; ni++) {
                const int n = n0 + wn + ni * 16 + lrow;
                float s  = fast_tanh(acc_s[mi][ni][r] + bs[n]);
                float tv = acc_t[mi][ni][r] + bt[n];
                const size_t oidx = (size_t)brow * NTX + 2 * n + parity;
                float val = fmaf(phi[oidx], __expf(s), tv);
                out[oidx] = val;
                if (Xout) Xout[(size_t)brow * NH + n] = f2bf(val);
                ssum += s;
            }
            // reduce over the 16 lanes sharing this output row
            ssum += __shfl_xor(ssum, 1);
            ssum += __shfl_xor(ssum, 2);
            ssum += __shfl_xor(ssum, 4);
            ssum += __shfl_xor(ssum, 8);
            if (lrow == 0) atomicAdd(ld + brow, ssum);
        }
    }
}

__global__ void finalize(const float* __restrict__ ld, float* __restrict__ out) {
    int i = blockIdx.x * blockDim.x + threadIdx.x;
    if (i < BATCH) out[(size_t)BATCH * NTX + i] = ld[i];
}

extern "C" void kernel_launch(void* const* d_in, const int* in_sizes, int n_in,
                              void* d_out, int out_size, void* d_ws, size_t ws_size,
                              hipStream_t stream) {
    const float* phi = (const float*)d_in[0];
    const float* Wsf = (const float*)d_in[1];
    const float* bs  = (const float*)d_in[2];
    const float* Wtf = (const float*)d_in[3];
    const float* bt  = (const float*)d_in[4];
    float* out = (float*)d_out;

    char* ws = (char*)d_ws;
    unsigned short* Bbf  = (unsigned short*)(ws);                 // 16,777,216 B
    unsigned short* Apbf = (unsigned short*)(ws + 16777216);      // 16,777,216 B
    unsigned short* Wsb  = (unsigned short*)(ws + 33554432);      //  8,388,608 B
    unsigned short* Wtb  = (unsigned short*)(ws + 41943040);      //  8,388,608 B
    float*          ld   = (float*)(ws + 50331648);               //     16,384 B

    prep<<<1024, 256, 0, stream>>>(phi, Wsf, Wtf, Bbf, Wsb, Wtb, ld);

    // coupling 1: A' = A*exp(s(B)) + t(B)  (A at odd flat slots: parity=1)
    coupling_gemm<<<dim3(32, 16), 256, 0, stream>>>(
        Bbf, Wsb, Wtb, bs, bt, phi, out, Apbf, ld, 1);

    // coupling 2: B' = B*exp(s(A')) + t(A') (B at even flat slots: parity=0)
    coupling_gemm<<<dim3(32, 16), 256, 0, stream>>>(
        Apbf, Wsb, Wtb, bs, bt, phi, out, nullptr, ld, 0);

    finalize<<<16, 256, 0, stream>>>(ld, out);
}